// Round 1
// baseline (1703.110 us; speedup 1.0000x reference)
//
#include <hip/hip_runtime.h>

#define NA_ 100000
#define NH_ 20000
#define E_  1000000
#define EL_ 200000
#define D_  128

// ---------------- CSR build ----------------

__global__ void count_edges_k(const int* __restrict__ d1, int* __restrict__ c1,
                              const int* __restrict__ d2, int* __restrict__ c2) {
  int i = blockIdx.x * 256 + threadIdx.x;
  if (i < E_) atomicAdd(&c1[d1[i]], 1);
  else if (i < 2 * E_) atomicAdd(&c2[d2[i - E_]], 1);
}

__global__ __launch_bounds__(1024) void scan2_k(const int* __restrict__ c1, int* __restrict__ o1, int n1,
                                                const int* __restrict__ c2, int* __restrict__ o2, int n2) {
  const int* c = blockIdx.x ? c2 : c1;
  int* o       = blockIdx.x ? o2 : o1;
  int n        = blockIdx.x ? n2 : n1;
  __shared__ int sums[1024];
  int t = threadIdx.x;
  int per = (n + 1023) >> 10;
  int s0 = t * per;
  int s1 = s0 + per; if (s1 > n) s1 = n;
  int loc = 0;
  for (int i = s0; i < s1; i++) loc += c[i];
  sums[t] = loc;
  __syncthreads();
  for (int sh = 1; sh < 1024; sh <<= 1) {
    int v = (t >= sh) ? sums[t - sh] : 0;
    __syncthreads();
    sums[t] += v;
    __syncthreads();
  }
  int run = (t == 0) ? 0 : sums[t - 1];
  for (int i = s0; i < s1; i++) { o[i] = run; run += c[i]; }
  if (t == 1023) o[n] = run;
}

__global__ void init_cur_k(const int* __restrict__ o1, int* __restrict__ cur1, int n1,
                           const int* __restrict__ o2, int* __restrict__ cur2, int n2) {
  int i = blockIdx.x * 256 + threadIdx.x;
  if (i < n1) cur1[i] = o1[i];
  else if (i < n1 + n2) cur2[i - n1] = o2[i - n1];
}

__global__ void fill_edges_k(const int* __restrict__ s1, const int* __restrict__ d1,
                             int* __restrict__ cur1, int* __restrict__ out1,
                             const int* __restrict__ s2, const int* __restrict__ d2,
                             int* __restrict__ cur2, int* __restrict__ out2) {
  int i = blockIdx.x * 256 + threadIdx.x;
  if (i < E_) {
    int p = atomicAdd(&cur1[d1[i]], 1);
    out1[p] = s1[i];
  } else if (i < 2 * E_) {
    int ii = i - E_;
    int p = atomicAdd(&cur2[d2[ii]], 1);
    out2[p] = s2[ii];
  }
}

// ---------------- mean aggregation (pull, one wave per dst row) ----------------

__global__ __launch_bounds__(256) void aggregate_k(const float* __restrict__ xsrc,
                                                   const int* __restrict__ off,
                                                   const int* __restrict__ srcs,
                                                   float* __restrict__ out, int ndst) {
  int w = (blockIdx.x * 256 + threadIdx.x) >> 6;  // global wave id == row
  int lane = threadIdx.x & 63;
  if (w >= ndst) return;
  int beg = off[w], end = off[w + 1];
  float ax0 = 0.f, ay0 = 0.f, ax1 = 0.f, ay1 = 0.f;
  const float* base = xsrc + 2 * lane;
  int j = beg;
  for (; j + 1 < end; j += 2) {
    int sA = srcs[j], sB = srcs[j + 1];
    float2 vA = *(const float2*)(base + (size_t)sA * D_);
    float2 vB = *(const float2*)(base + (size_t)sB * D_);
    ax0 += vA.x; ay0 += vA.y;
    ax1 += vB.x; ay1 += vB.y;
  }
  if (j < end) {
    int sA = srcs[j];
    float2 vA = *(const float2*)(base + (size_t)sA * D_);
    ax0 += vA.x; ay0 += vA.y;
  }
  int deg = end - beg;
  float scale = 1.0f / (float)(deg > 0 ? deg : 1);
  float2 r;
  r.x = (ax0 + ax1) * scale;
  r.y = (ay0 + ay1) * scale;
  *(float2*)(out + (size_t)w * D_ + 2 * lane) = r;
}

// ---------------- SAGE dense: out = [relu]( A@Wl + bl + X@Wr ) ----------------
// block: 256 threads, 32 rows x 128 cols; thread: 8 rows x 2 cols

template <bool RELU>
__global__ __launch_bounds__(256) void sage_gemm_k(const float* __restrict__ A, const float* __restrict__ X,
                                                   const float* __restrict__ Wl, const float* __restrict__ bl,
                                                   const float* __restrict__ Wr,
                                                   float* __restrict__ out, int rows) {
  __shared__ float as_[32][128];
  __shared__ float xs_[32][128];
  const int t = threadIdx.x;
  const int rb = blockIdx.x * 32;
  for (int idx = t; idx < 32 * 128; idx += 256) {
    int i = idx >> 7, k = idx & 127;
    int r = rb + i;
    float a = 0.f, x = 0.f;
    if (r < rows) {
      a = A[(size_t)r * D_ + k];
      x = X[(size_t)r * D_ + k];
    }
    as_[i][k] = a;
    xs_[i][k] = x;
  }
  __syncthreads();
  const int n0 = t & 63;
  const int g  = t >> 6;  // wave id, rows g*8 .. g*8+7
  float acc0[8], acc1[8];
  const float b0 = bl[n0], b1v = bl[n0 + 64];
#pragma unroll
  for (int j = 0; j < 8; j++) { acc0[j] = b0; acc1[j] = b1v; }
  for (int k4 = 0; k4 < 32; k4++) {
    const int k0 = k4 * 4;
    float wl[4][2], wr[4][2];
#pragma unroll
    for (int q = 0; q < 4; q++) {
      wl[q][0] = Wl[(k0 + q) * 128 + n0];
      wl[q][1] = Wl[(k0 + q) * 128 + n0 + 64];
      wr[q][0] = Wr[(k0 + q) * 128 + n0];
      wr[q][1] = Wr[(k0 + q) * 128 + n0 + 64];
    }
#pragma unroll
    for (int j = 0; j < 8; j++) {
      const int i = g * 8 + j;
      float4 a4 = *(const float4*)&as_[i][k0];
      float4 x4 = *(const float4*)&xs_[i][k0];
      acc0[j] += a4.x * wl[0][0] + a4.y * wl[1][0] + a4.z * wl[2][0] + a4.w * wl[3][0]
               + x4.x * wr[0][0] + x4.y * wr[1][0] + x4.z * wr[2][0] + x4.w * wr[3][0];
      acc1[j] += a4.x * wl[0][1] + a4.y * wl[1][1] + a4.z * wl[2][1] + a4.w * wl[3][1]
               + x4.x * wr[0][1] + x4.y * wr[1][1] + x4.z * wr[2][1] + x4.w * wr[3][1];
    }
  }
#pragma unroll
  for (int j = 0; j < 8; j++) {
    int r = rb + g * 8 + j;
    if (r < rows) {
      float v0 = acc0[j], v1 = acc1[j];
      if (RELU) { v0 = fmaxf(v0, 0.f); v1 = fmaxf(v1, 0.f); }
      out[(size_t)r * D_ + n0] = v0;
      out[(size_t)r * D_ + n0 + 64] = v1;
    }
  }
}

// ---------------- decoder: z1 = [Za[row]|Zh[col]]; z2 = relu(z1@W1+b1); pred = z2@W2+b2 ----------------

__global__ __launch_bounds__(256) void decoder_k(const float* __restrict__ Za, const float* __restrict__ Zh,
                                                 const int* __restrict__ rowi, const int* __restrict__ coli,
                                                 const float* __restrict__ W1, const float* __restrict__ b1,
                                                 const float* __restrict__ W2, const float* __restrict__ b2,
                                                 float* __restrict__ pred, float* __restrict__ z1o,
                                                 float* __restrict__ z2o) {
  __shared__ float z1s[32 * 256];
  __shared__ int ra[32], rc[32];
  const int t = threadIdx.x;
  const int rb = blockIdx.x * 32;
  if (t < 32) {
    int r = rb + t;
    ra[t] = (r < EL_) ? rowi[r] : -1;
    rc[t] = (r < EL_) ? coli[r] : 0;
  }
  __syncthreads();
  for (int i = 0; i < 32; i++) {
    int k = t;  // 0..255
    float v = 0.f;
    int a = ra[i];
    if (a >= 0) v = (k < 128) ? Za[(size_t)a * 128 + k] : Zh[(size_t)rc[i] * 128 + (k - 128)];
    z1s[i * 256 + k] = v;
    int r = rb + i;
    if (a >= 0) z1o[(size_t)r * 256 + k] = v;
  }
  __syncthreads();
  const int n0 = t & 63;
  const int g  = t >> 6;
  float acc0[8], acc1[8];
  const float bb0 = b1[n0], bb1 = b1[n0 + 64];
#pragma unroll
  for (int j = 0; j < 8; j++) { acc0[j] = bb0; acc1[j] = bb1; }
  for (int k4 = 0; k4 < 64; k4++) {
    const int k0 = k4 * 4;
    float w[4][2];
#pragma unroll
    for (int q = 0; q < 4; q++) {
      w[q][0] = W1[(k0 + q) * 128 + n0];
      w[q][1] = W1[(k0 + q) * 128 + n0 + 64];
    }
#pragma unroll
    for (int j = 0; j < 8; j++) {
      float4 a4 = *(const float4*)&z1s[(g * 8 + j) * 256 + k0];
      acc0[j] += a4.x * w[0][0] + a4.y * w[1][0] + a4.z * w[2][0] + a4.w * w[3][0];
      acc1[j] += a4.x * w[0][1] + a4.y * w[1][1] + a4.z * w[2][1] + a4.w * w[3][1];
    }
  }
  const float w2a = W2[n0], w2b = W2[n0 + 64];
  __syncthreads();  // done reading z1s; reuse as reduction scratch
  float* red = z1s;  // 32*128 region
#pragma unroll
  for (int j = 0; j < 8; j++) {
    int i = g * 8 + j;
    int r = rb + i;
    float v0 = fmaxf(acc0[j], 0.f), v1 = fmaxf(acc1[j], 0.f);
    if (r < EL_) {
      z2o[(size_t)r * 128 + n0] = v0;
      z2o[(size_t)r * 128 + n0 + 64] = v1;
    }
    red[i * 128 + n0] = v0 * w2a;
    red[i * 128 + n0 + 64] = v1 * w2b;
  }
  __syncthreads();
  const int lane = t & 63;
  const float bias2 = b2[0];
  for (int q = 0; q < 8; q++) {
    int i = g * 8 + q;
    float s = red[i * 128 + lane] + red[i * 128 + 64 + lane];
    for (int off = 32; off; off >>= 1) s += __shfl_down(s, off);
    if (lane == 0) {
      int r = rb + i;
      if (r < EL_) pred[r] = s + bias2;
    }
  }
}

// ---------------- host ----------------

static inline char* carve(char*& p, size_t bytes) {
  char* r = p;
  p += (bytes + 255) & ~(size_t)255;
  return r;
}

extern "C" void kernel_launch(void* const* d_in, const int* in_sizes, int n_in,
                              void* d_out, int out_size, void* d_ws, size_t ws_size,
                              hipStream_t stream) {
  const float* x_author = (const float*)d_in[0];
  const float* x_hotel  = (const float*)d_in[1];
  const int* ei_ah_src  = (const int*)d_in[2];
  const int* ei_ah_dst  = (const int*)d_in[3];
  const int* ei_ha_src  = (const int*)d_in[4];
  const int* ei_ha_dst  = (const int*)d_in[5];
  const int* eli_row    = (const int*)d_in[6];
  const int* eli_col    = (const int*)d_in[7];
  const float* W1_ah_l  = (const float*)d_in[8];
  const float* W1_ah_r  = (const float*)d_in[9];
  const float* W1_ha_l  = (const float*)d_in[10];
  const float* W1_ha_r  = (const float*)d_in[11];
  const float* W2_ah_l  = (const float*)d_in[12];
  const float* W2_ah_r  = (const float*)d_in[13];
  const float* W2_ha_l  = (const float*)d_in[14];
  const float* W2_ha_r  = (const float*)d_in[15];
  const float* b1_ah_l  = (const float*)d_in[16];
  const float* b1_ha_l  = (const float*)d_in[17];
  const float* b2_ah_l  = (const float*)d_in[18];
  const float* b2_ha_l  = (const float*)d_in[19];
  const float* W_lin1   = (const float*)d_in[20];
  const float* b_lin1   = (const float*)d_in[21];
  const float* W_lin2   = (const float*)d_in[22];
  const float* b_lin2   = (const float*)d_in[23];

  char* p = (char*)d_ws;
  float* A_h = (float*)carve(p, (size_t)NH_ * D_ * 4);
  float* A_a = (float*)carve(p, (size_t)NA_ * D_ * 4);
  float* H_h = (float*)carve(p, (size_t)NH_ * D_ * 4);
  float* H_a = (float*)carve(p, (size_t)NA_ * D_ * 4);
  float* Z_h = (float*)carve(p, (size_t)NH_ * D_ * 4);
  float* Z_a = (float*)carve(p, (size_t)NA_ * D_ * 4);
  int* off_h = (int*)carve(p, (size_t)(NH_ + 1) * 4);
  int* off_a = (int*)carve(p, (size_t)(NA_ + 1) * 4);
  int* cur_h = (int*)carve(p, (size_t)(NH_ + NA_) * 4);  // cur_h then cur_a contiguous
  int* cur_a = cur_h + NH_;
  int* s_ah  = (int*)carve(p, (size_t)E_ * 4);
  int* s_ha  = (int*)carve(p, (size_t)E_ * 4);

  float* pred = (float*)d_out;
  float* z1o  = pred + EL_;
  float* z2o  = z1o + (size_t)EL_ * 256;

  // --- CSR build (shared by both layers) ---
  hipMemsetAsync(cur_h, 0, (size_t)(NH_ + NA_) * 4, stream);
  count_edges_k<<<(2 * E_ + 255) / 256, 256, 0, stream>>>(ei_ah_dst, cur_h, ei_ha_dst, cur_a);
  scan2_k<<<2, 1024, 0, stream>>>(cur_h, off_h, NH_, cur_a, off_a, NA_);
  init_cur_k<<<(NH_ + NA_ + 255) / 256, 256, 0, stream>>>(off_h, cur_h, NH_, off_a, cur_a, NA_);
  fill_edges_k<<<(2 * E_ + 255) / 256, 256, 0, stream>>>(ei_ah_src, ei_ah_dst, cur_h, s_ah,
                                                         ei_ha_src, ei_ha_dst, cur_a, s_ha);

  // --- layer 1 ---
  aggregate_k<<<(NH_ + 3) / 4, 256, 0, stream>>>(x_author, off_h, s_ah, A_h, NH_);
  sage_gemm_k<true><<<(NH_ + 31) / 32, 256, 0, stream>>>(A_h, x_hotel, W1_ah_l, b1_ah_l, W1_ah_r, H_h, NH_);
  aggregate_k<<<(NA_ + 3) / 4, 256, 0, stream>>>(x_hotel, off_a, s_ha, A_a, NA_);
  sage_gemm_k<true><<<(NA_ + 31) / 32, 256, 0, stream>>>(A_a, x_author, W1_ha_l, b1_ha_l, W1_ha_r, H_a, NA_);

  // --- layer 2 ---
  aggregate_k<<<(NH_ + 3) / 4, 256, 0, stream>>>(H_a, off_h, s_ah, A_h, NH_);
  sage_gemm_k<false><<<(NH_ + 31) / 32, 256, 0, stream>>>(A_h, H_h, W2_ah_l, b2_ah_l, W2_ah_r, Z_h, NH_);
  aggregate_k<<<(NA_ + 3) / 4, 256, 0, stream>>>(H_h, off_a, s_ha, A_a, NA_);
  sage_gemm_k<false><<<(NA_ + 31) / 32, 256, 0, stream>>>(A_a, H_a, W2_ha_l, b2_ha_l, W2_ha_r, Z_a, NA_);

  // --- decoder ---
  decoder_k<<<(EL_ + 31) / 32, 256, 0, stream>>>(Z_a, Z_h, eli_row, eli_col,
                                                 W_lin1, b_lin1, W_lin2, b_lin2,
                                                 pred, z1o, z2o);
}

// Round 2
// 1194.160 us; speedup vs baseline: 1.4262x; 1.4262x over previous
//
#include <hip/hip_runtime.h>

#define NA_ 100000
#define NH_ 20000
#define E_  1000000
#define EL_ 200000
#define D_  128

typedef __attribute__((ext_vector_type(8))) short short8;
typedef __attribute__((ext_vector_type(4))) float f32x4;

__device__ __forceinline__ ushort f2bf(float f) {
  union { float f; uint u; } v; v.f = f;
  uint u = v.u;
  return (ushort)((u + 0x7FFFu + ((u >> 16) & 1u)) >> 16);
}
__device__ __forceinline__ uint pack2bf(float a, float b) {
  return (uint)f2bf(a) | ((uint)f2bf(b) << 16);
}

// ---------------- CSR build ----------------

__global__ void count_edges_k(const int* __restrict__ d1, int* __restrict__ c1,
                              const int* __restrict__ d2, int* __restrict__ c2) {
  int i = blockIdx.x * 256 + threadIdx.x;
  if (i < E_) atomicAdd(&c1[d1[i]], 1);
  else if (i < 2 * E_) atomicAdd(&c2[d2[i - E_]], 1);
}

__global__ __launch_bounds__(1024) void scan2_k(const int* __restrict__ c1, int* __restrict__ o1, int n1,
                                                const int* __restrict__ c2, int* __restrict__ o2, int n2) {
  const int* c = blockIdx.x ? c2 : c1;
  int* o       = blockIdx.x ? o2 : o1;
  int n        = blockIdx.x ? n2 : n1;
  __shared__ int sums[1024];
  int t = threadIdx.x;
  int per = (n + 1023) >> 10;
  int s0 = t * per;
  int s1 = s0 + per; if (s1 > n) s1 = n;
  int loc = 0;
  for (int i = s0; i < s1; i++) loc += c[i];
  sums[t] = loc;
  __syncthreads();
  for (int sh = 1; sh < 1024; sh <<= 1) {
    int v = (t >= sh) ? sums[t - sh] : 0;
    __syncthreads();
    sums[t] += v;
    __syncthreads();
  }
  int run = (t == 0) ? 0 : sums[t - 1];
  for (int i = s0; i < s1; i++) { o[i] = run; run += c[i]; }
  if (t == 1023) o[n] = run;
}

__global__ void init_cur_k(const int* __restrict__ o1, int* __restrict__ cur1, int n1,
                           const int* __restrict__ o2, int* __restrict__ cur2, int n2) {
  int i = blockIdx.x * 256 + threadIdx.x;
  if (i < n1) cur1[i] = o1[i];
  else if (i < n1 + n2) cur2[i - n1] = o2[i - n1];
}

__global__ void fill_edges_k(const int* __restrict__ s1, const int* __restrict__ d1,
                             int* __restrict__ cur1, int* __restrict__ out1,
                             const int* __restrict__ s2, const int* __restrict__ d2,
                             int* __restrict__ cur2, int* __restrict__ out2) {
  int i = blockIdx.x * 256 + threadIdx.x;
  if (i < E_) {
    int p = atomicAdd(&cur1[d1[i]], 1);
    out1[p] = s1[i];
  } else if (i < 2 * E_) {
    int ii = i - E_;
    int p = atomicAdd(&cur2[d2[ii]], 1);
    out2[p] = s2[ii];
  }
}

// ---------------- fp32 -> bf16 conversion of both feature matrices ----------------

__global__ void cvt_bf_k(const float* __restrict__ xa, ushort* __restrict__ da,
                         const float* __restrict__ xh, ushort* __restrict__ dh) {
  int i = blockIdx.x * 256 + threadIdx.x;  // one dword (2 floats) per thread
  const int na2 = NA_ * 64;
  if (i < na2) {
    float2 v = *(const float2*)(xa + (size_t)i * 2);
    ((uint*)da)[i] = pack2bf(v.x, v.y);
  } else {
    int k = i - na2;
    if (k < NH_ * 64) {
      float2 v = *(const float2*)(xh + (size_t)k * 2);
      ((uint*)dh)[k] = pack2bf(v.x, v.y);
    }
  }
}

// ---------------- pack [Wl;Wr] (K=256, N=128) into MFMA B-frag layout, bf16 ----------------
// dst[((kc*8+nt)*64 + lane)*8 + j] = W[kc*32 + (lane>>4)*8 + j][nt*16 + (lane&15)]

__global__ void pack_all_k(const float* a0, const float* a1, ushort* ad,
                           const float* b0, const float* b1, ushort* bd,
                           const float* c0, const float* c1, ushort* cd,
                           const float* d0, const float* d1, ushort* dd,
                           const float* e0, const float* e1, ushort* ed) {
  const float *s0, *s1; ushort* dst;
  switch (blockIdx.y) {
    case 0: s0 = a0; s1 = a1; dst = ad; break;
    case 1: s0 = b0; s1 = b1; dst = bd; break;
    case 2: s0 = c0; s1 = c1; dst = cd; break;
    case 3: s0 = d0; s1 = d1; dst = dd; break;
    default: s0 = e0; s1 = e1; dst = ed; break;
  }
  int idx = blockIdx.x * 256 + threadIdx.x;  // 0..32767
  int j = idx & 7, lane = (idx >> 3) & 63, nt = (idx >> 9) & 7, kc = idx >> 12;
  int k = kc * 32 + (lane >> 4) * 8 + j;
  int n = nt * 16 + (lane & 15);
  float v = (k < 128) ? s0[k * 128 + n] : s1[(k - 128) * 128 + n];
  dst[idx] = f2bf(v);
}

// ---------------- mean aggregation (pull, one wave per dst row, bf16 rows) ----------------

__global__ __launch_bounds__(256) void aggregate_bf_k(const ushort* __restrict__ xsrc,
                                                      const int* __restrict__ off,
                                                      const int* __restrict__ srcs,
                                                      ushort* __restrict__ out, int ndst) {
  int w = (blockIdx.x * 256 + threadIdx.x) >> 6;
  int lane = threadIdx.x & 63;
  if (w >= ndst) return;
  int beg = off[w], end = off[w + 1];
  float a0 = 0.f, a1 = 0.f, b0 = 0.f, b1 = 0.f;
  const ushort* base = xsrc + lane * 2;
  int j = beg;
  for (; j + 1 < end; j += 2) {
    int sA = srcs[j], sB = srcs[j + 1];
    uint vA = *(const uint*)(base + (size_t)sA * 128);
    uint vB = *(const uint*)(base + (size_t)sB * 128);
    a0 += __uint_as_float(vA << 16); a1 += __uint_as_float(vA & 0xFFFF0000u);
    b0 += __uint_as_float(vB << 16); b1 += __uint_as_float(vB & 0xFFFF0000u);
  }
  if (j < end) {
    uint vA = *(const uint*)(base + (size_t)srcs[j] * 128);
    a0 += __uint_as_float(vA << 16); a1 += __uint_as_float(vA & 0xFFFF0000u);
  }
  int deg = end - beg;
  float sc = 1.0f / (float)(deg > 0 ? deg : 1);
  *(uint*)(out + (size_t)w * 128 + lane * 2) = pack2bf((a0 + b0) * sc, (a1 + b1) * sc);
}

// ---------------- SAGE transform via MFMA: out = act([A|X] @ Wp + bias) ----------------
// block = 256 thr = 4 waves, 64 rows/block (16 rows/wave), full N=128, K=256.

template <bool RELU, bool OUTBF>
__global__ __launch_bounds__(256) void sage_mfma_k(const ushort* __restrict__ Abf,
                                                   const ushort* __restrict__ Xbf,
                                                   const ushort* __restrict__ Wp,
                                                   const float* __restrict__ bias,
                                                   float* __restrict__ outF,
                                                   ushort* __restrict__ outB, int rows) {
  const int t = threadIdx.x;
  const int w = t >> 6, lane = t & 63, quad = lane >> 4, m = lane & 15;
  const int row0 = blockIdx.x * 64 + w * 16;
  int rA = row0 + m; if (rA >= rows) rA = rows - 1;
  f32x4 acc[8];
#pragma unroll
  for (int nt = 0; nt < 8; nt++) acc[nt] = (f32x4){0.f, 0.f, 0.f, 0.f};
#pragma unroll
  for (int kc = 0; kc < 8; kc++) {
    const ushort* src = (kc < 4) ? (Abf + (size_t)rA * 128 + kc * 32)
                                 : (Xbf + (size_t)rA * 128 + (kc - 4) * 32);
    short8 a = *(const short8*)(src + quad * 8);
    const ushort* wp = Wp + (size_t)(kc * 8) * 512 + lane * 8;
#pragma unroll
    for (int nt = 0; nt < 8; nt++) {
      short8 b = *(const short8*)(wp + nt * 512);
      acc[nt] = __builtin_amdgcn_mfma_f32_16x16x32_bf16(a, b, acc[nt], 0, 0, 0);
    }
  }
#pragma unroll
  for (int nt = 0; nt < 8; nt++) {
    float bv = bias[nt * 16 + m];
#pragma unroll
    for (int r = 0; r < 4; r++) {
      int row = row0 + quad * 4 + r;
      if (row < rows) {
        float v = acc[nt][r] + bv;
        if (RELU) v = fmaxf(v, 0.f);
        if (OUTBF) outB[(size_t)row * 128 + nt * 16 + m] = f2bf(v);
        else       outF[(size_t)row * 128 + nt * 16 + m] = v;
      }
    }
  }
}

// ---------------- decoder: gather z1 (fp32 out + bf16 LDS) -> MFMA z2 -> pred ----------------
// block = 256 thr = 4 waves, 64 edges/block. EL % 64 == 0.

__global__ __launch_bounds__(256) void decoder_mfma_k(const float* __restrict__ Za,
                                                      const float* __restrict__ Zh,
                                                      const int* __restrict__ rowi,
                                                      const int* __restrict__ coli,
                                                      const ushort* __restrict__ Wp,
                                                      const float* __restrict__ b1,
                                                      const float* __restrict__ W2,
                                                      const float* __restrict__ b2,
                                                      float* __restrict__ pred,
                                                      float* __restrict__ z1o,
                                                      float* __restrict__ z2o) {
  __shared__ ushort z1bf[64 * 264];  // row stride 264 bf16 = 528 B (16B-aligned, 2-way banks)
  __shared__ int ra[64], rc[64];
  const int t = threadIdx.x, w = t >> 6, lane = t & 63, quad = lane >> 4, m = lane & 15;
  const int rb = blockIdx.x * 64;
  if (t < 64) ra[t] = rowi[rb + t];
  else if (t < 128) rc[t - 64] = coli[rb + t - 64];
  __syncthreads();
#pragma unroll 4
  for (int rr = 0; rr < 16; rr++) {
    int row = w * 16 + rr;
    int a = ra[row], c = rc[row];
    float2 va = *(const float2*)(Za + (size_t)a * 128 + lane * 2);
    float2 vc = *(const float2*)(Zh + (size_t)c * 128 + lane * 2);
    float* zr = z1o + (size_t)(rb + row) * 256;
    *(float2*)(zr + lane * 2) = va;
    *(float2*)(zr + 128 + lane * 2) = vc;
    uint* lbase = (uint*)(z1bf + row * 264);
    lbase[lane] = pack2bf(va.x, va.y);
    lbase[64 + lane] = pack2bf(vc.x, vc.y);
  }
  __syncthreads();
  f32x4 acc[8];
#pragma unroll
  for (int nt = 0; nt < 8; nt++) acc[nt] = (f32x4){0.f, 0.f, 0.f, 0.f};
#pragma unroll
  for (int kc = 0; kc < 8; kc++) {
    short8 a = *(const short8*)(z1bf + (w * 16 + m) * 264 + kc * 32 + quad * 8);
    const ushort* wp = Wp + (size_t)(kc * 8) * 512 + lane * 8;
#pragma unroll
    for (int nt = 0; nt < 8; nt++) {
      short8 b = *(const short8*)(wp + nt * 512);
      acc[nt] = __builtin_amdgcn_mfma_f32_16x16x32_bf16(a, b, acc[nt], 0, 0, 0);
    }
  }
  float part[4] = {0.f, 0.f, 0.f, 0.f};
#pragma unroll
  for (int nt = 0; nt < 8; nt++) {
    float bv = b1[nt * 16 + m];
    float wv = W2[nt * 16 + m];
#pragma unroll
    for (int r = 0; r < 4; r++) {
      float v = fmaxf(acc[nt][r] + bv, 0.f);
      z2o[(size_t)(rb + w * 16 + quad * 4 + r) * 128 + nt * 16 + m] = v;
      part[r] += v * wv;
    }
  }
  const float bias2 = b2[0];
#pragma unroll
  for (int r = 0; r < 4; r++) {
    float s = part[r];
    s += __shfl_xor(s, 1); s += __shfl_xor(s, 2);
    s += __shfl_xor(s, 4); s += __shfl_xor(s, 8);
    if (m == 0) pred[rb + w * 16 + quad * 4 + r] = s + bias2;
  }
}

// ---------------- host ----------------

static inline char* carve(char*& p, size_t bytes) {
  char* r = p;
  p += (bytes + 255) & ~(size_t)255;
  return r;
}

extern "C" void kernel_launch(void* const* d_in, const int* in_sizes, int n_in,
                              void* d_out, int out_size, void* d_ws, size_t ws_size,
                              hipStream_t stream) {
  const float* x_author = (const float*)d_in[0];
  const float* x_hotel  = (const float*)d_in[1];
  const int* ei_ah_src  = (const int*)d_in[2];
  const int* ei_ah_dst  = (const int*)d_in[3];
  const int* ei_ha_src  = (const int*)d_in[4];
  const int* ei_ha_dst  = (const int*)d_in[5];
  const int* eli_row    = (const int*)d_in[6];
  const int* eli_col    = (const int*)d_in[7];
  const float* W1_ah_l  = (const float*)d_in[8];
  const float* W1_ah_r  = (const float*)d_in[9];
  const float* W1_ha_l  = (const float*)d_in[10];
  const float* W1_ha_r  = (const float*)d_in[11];
  const float* W2_ah_l  = (const float*)d_in[12];
  const float* W2_ah_r  = (const float*)d_in[13];
  const float* W2_ha_l  = (const float*)d_in[14];
  const float* W2_ha_r  = (const float*)d_in[15];
  const float* b1_ah_l  = (const float*)d_in[16];
  const float* b1_ha_l  = (const float*)d_in[17];
  const float* b2_ah_l  = (const float*)d_in[18];
  const float* b2_ha_l  = (const float*)d_in[19];
  const float* W_lin1   = (const float*)d_in[20];
  const float* b_lin1   = (const float*)d_in[21];
  const float* W_lin2   = (const float*)d_in[22];
  const float* b_lin2   = (const float*)d_in[23];

  char* p = (char*)d_ws;
  ushort* xa_bf = (ushort*)carve(p, (size_t)NA_ * D_ * 2);
  ushort* xh_bf = (ushort*)carve(p, (size_t)NH_ * D_ * 2);
  ushort* A_hbf = (ushort*)carve(p, (size_t)NH_ * D_ * 2);
  ushort* A_abf = (ushort*)carve(p, (size_t)NA_ * D_ * 2);
  ushort* H_hbf = (ushort*)carve(p, (size_t)NH_ * D_ * 2);
  ushort* H_abf = (ushort*)carve(p, (size_t)NA_ * D_ * 2);
  float*  Z_h   = (float*)carve(p, (size_t)NH_ * D_ * 4);
  float*  Z_a   = (float*)carve(p, (size_t)NA_ * D_ * 4);
  ushort* Wp1ah = (ushort*)carve(p, 32768 * 2);
  ushort* Wp1ha = (ushort*)carve(p, 32768 * 2);
  ushort* Wp2ah = (ushort*)carve(p, 32768 * 2);
  ushort* Wp2ha = (ushort*)carve(p, 32768 * 2);
  ushort* WpD   = (ushort*)carve(p, 32768 * 2);
  int* off_h = (int*)carve(p, (size_t)(NH_ + 1) * 4);
  int* off_a = (int*)carve(p, (size_t)(NA_ + 1) * 4);
  int* cur_h = (int*)carve(p, (size_t)(NH_ + NA_) * 4);
  int* cur_a = cur_h + NH_;
  int* s_ah  = (int*)carve(p, (size_t)E_ * 4);
  int* s_ha  = (int*)carve(p, (size_t)E_ * 4);

  float* pred = (float*)d_out;
  float* z1o  = pred + EL_;
  float* z2o  = z1o + (size_t)EL_ * 256;

  // --- CSR build (shared by both layers) ---
  hipMemsetAsync(cur_h, 0, (size_t)(NH_ + NA_) * 4, stream);
  count_edges_k<<<(2 * E_ + 255) / 256, 256, 0, stream>>>(ei_ah_dst, cur_h, ei_ha_dst, cur_a);
  scan2_k<<<2, 1024, 0, stream>>>(cur_h, off_h, NH_, cur_a, off_a, NA_);
  init_cur_k<<<(NH_ + NA_ + 255) / 256, 256, 0, stream>>>(off_h, cur_h, NH_, off_a, cur_a, NA_);
  fill_edges_k<<<(2 * E_ + 255) / 256, 256, 0, stream>>>(ei_ah_src, ei_ah_dst, cur_h, s_ah,
                                                         ei_ha_src, ei_ha_dst, cur_a, s_ha);

  // --- bf16 conversions + weight packing ---
  cvt_bf_k<<<(NA_ * 64 + NH_ * 64 + 255) / 256, 256, 0, stream>>>(x_author, xa_bf, x_hotel, xh_bf);
  dim3 pg(128, 5);
  pack_all_k<<<pg, 256, 0, stream>>>(W1_ah_l, W1_ah_r, Wp1ah,
                                     W1_ha_l, W1_ha_r, Wp1ha,
                                     W2_ah_l, W2_ah_r, Wp2ah,
                                     W2_ha_l, W2_ha_r, Wp2ha,
                                     W_lin1, W_lin1 + 128 * 128, WpD);

  // --- layer 1 ---
  aggregate_bf_k<<<(NH_ + 3) / 4, 256, 0, stream>>>(xa_bf, off_h, s_ah, A_hbf, NH_);
  sage_mfma_k<true, true><<<(NH_ + 63) / 64, 256, 0, stream>>>(A_hbf, xh_bf, Wp1ah, b1_ah_l, nullptr, H_hbf, NH_);
  aggregate_bf_k<<<(NA_ + 3) / 4, 256, 0, stream>>>(xh_bf, off_a, s_ha, A_abf, NA_);
  sage_mfma_k<true, true><<<(NA_ + 63) / 64, 256, 0, stream>>>(A_abf, xa_bf, Wp1ha, b1_ha_l, nullptr, H_abf, NA_);

  // --- layer 2 (fp32 outputs) ---
  aggregate_bf_k<<<(NH_ + 3) / 4, 256, 0, stream>>>(H_abf, off_h, s_ah, A_hbf, NH_);
  sage_mfma_k<false, false><<<(NH_ + 63) / 64, 256, 0, stream>>>(A_hbf, H_hbf, Wp2ah, b2_ah_l, Z_h, nullptr, NH_);
  aggregate_bf_k<<<(NA_ + 3) / 4, 256, 0, stream>>>(H_hbf, off_a, s_ha, A_abf, NA_);
  sage_mfma_k<false, false><<<(NA_ + 63) / 64, 256, 0, stream>>>(A_abf, H_abf, Wp2ha, b2_ha_l, Z_a, nullptr, NA_);

  // --- decoder ---
  decoder_mfma_k<<<EL_ / 64, 256, 0, stream>>>(Z_a, Z_h, eli_row, eli_col,
                                               WpD, b_lin1, W_lin2, b_lin2,
                                               pred, z1o, z2o);
}